// Round 1
// baseline (187.108 us; speedup 1.0000x reference)
//
#include <hip/hip_runtime.h>
#include <math.h>

// BERT-CRF forward NLL on MI355X — register-only serial recursion, one item
// per 64-lane wave, p duplicated mod 32 across halves.
//
// This revision halves the serial dependency depth of the per-step 32x32
// matvec: instead of two 16-deep DPP rotation chains (rotl 0..15, rotr 1..16),
// we run FOUR 8-deep chains. Chains A/B start from p (rotl 0..7 / rotr 1..8);
// chains C/D start from x16 = ring-rotation-by-16 of p, obtained with a single
// ds_swizzle xor-16 (offset 0x401F; xor of bit4 == +16 mod 32, bijective and
// ring-consistent so rotl1/rotr1 still walk the ring). Coverage per dest lane:
//   A: j..j+7   B: j-1..j-8   C: j+16..j+23   D: j+15..j+8   == all 32 sources.
// Instruction count per step is unchanged; only the critical chain shortens.

constexpr int NTAG = 32;
constexpr int TSTART = 30;
constexpr int TSTOP = 31;
constexpr int NB = 1024;
constexpr int NS = 512;

constexpr float LOG2E = 1.44269504088896340736f;
constexpr float LN2   = 0.69314718055994530942f;

__device__ __forceinline__ float rotl1(float x) {  // dst[i] = src[(i+1)%64]
    return __int_as_float(__builtin_amdgcn_update_dpp(
        0, __float_as_int(x), 0x134 /*wave_rol:1*/, 0xF, 0xF, false));
}
__device__ __forceinline__ float rotr1(float x) {  // dst[i] = src[(i-1)%64]
    return __int_as_float(__builtin_amdgcn_update_dpp(
        0, __float_as_int(x), 0x13C /*wave_ror:1*/, 0xF, 0xF, false));
}
__device__ __forceinline__ float xor16(float x) {  // dst[i] = src[i^16] (32-grp)
    return __int_as_float(__builtin_amdgcn_ds_swizzle(
        __float_as_int(x), 0x401F /*bitmode xor=0x10 and=0x1F*/));
}
__device__ __forceinline__ float fexp2(float x) {
#if __has_builtin(__builtin_amdgcn_exp2f)
    return __builtin_amdgcn_exp2f(x);
#else
    return exp2f(x);
#endif
}

__global__ __launch_bounds__(64)
void crf_fwd(const float* __restrict__ feats,
             const int*   __restrict__ labels,
             const int*   __restrict__ lengths,
             const float* __restrict__ trans,
             float*       __restrict__ out)
{
    const int j   = threadIdx.x;   // 0..63
    const int j32 = j & 31;
    const int b   = blockIdx.x;

    // Per-lane E coefficients (exp of trans), indexed by chain level.
    // EA[r][lane j] = exp(trans[(j+r)&31][j&31])      r = 0..7   (rol from p)
    // EB[s][lane j] = exp(trans[(j-s)&31][j&31])      s = 1..8   (ror from p)
    // EC[r][lane j] = exp(trans[(j+16+r)&31][j&31])   r = 0..7   (rol from x16)
    // ED[s][lane j] = exp(trans[(j+16-s)&31][j&31])   s = 1..8   (ror from x16)
    float EA[8], EB[8], EC[8], ED[8];
    #pragma unroll
    for (int r = 0; r < 8; ++r) {
        EA[r] = fexp2(trans[(((j32 + r) & 31) << 5) + j32] * LOG2E);
        EC[r] = fexp2(trans[(((j32 + 16 + r) & 31) << 5) + j32] * LOG2E);
    }
    #pragma unroll
    for (int s = 1; s <= 8; ++s) {
        EB[s - 1] = fexp2(trans[(((j32 - s) & 31) << 5) + j32] * LOG2E);
        ED[s - 1] = fexp2(trans[(((j32 + 16 - s) & 31) << 5) + j32] * LOG2E);
    }

    const int len = lengths[b];
    const float* fb = feats  + (size_t)b * NS * NTAG;
    const int*   lb = labels + (size_t)b * NS;

    // labels for this item, staged into registers (coalesced, off the loop)
    int labr[8];
    #pragma unroll
    for (int k = 0; k < 8; ++k)
        labr[k] = lb[(k << 6) + j];

    // t = 0
    float feat0 = fb[j32];
    float p = fexp2((feat0 + trans[(TSTART << 5) + j32]) * LOG2E);

    int bits0 = __builtin_amdgcn_readfirstlane(__float_as_int(p));
    int e0    = min(max((bits0 >> 23) & 0xFF, 1), 254);
    int kreg  = e0 - 127;
    int creg  = 0;

    // feats prefetch pipeline (8 deep)
    float pf[8];
    #pragma unroll
    for (int u = 0; u < 8; ++u) {
        int tt = min(1 + u, NS - 1);
        pf[u] = fb[(size_t)tt * NTAG + j32];
    }

    const int nsteps = len - 1;        // recursion steps t = 1..len-1
    const int nchunk = nsteps >> 3;
    const int rem    = nsteps & 7;
    int t = 1;

    #define CRF_STEP(FEAT)                                                   \
    {                                                                        \
        float feat_ = (FEAT);                                                \
        float x16_  = xor16(p);         /* ring+16, issued first */          \
        /* off-chain: emission factor with folded 2^-k */                    \
        creg += kreg;                                                        \
        float kf = (float)kreg;                                              \
        float F  = fexp2(fmaf(feat_, LOG2E, -kf));                           \
        /* critical chain: four 8-deep DPP rotation chains */                \
        float RA = p,    LB = p;                                             \
        float RC = x16_, LD = x16_;                                          \
        float accA = p    * EA[0];                                           \
        float accC = x16_ * EC[0];                                           \
        LB = rotr1(LB); float accB = LB * EB[0];                             \
        LD = rotr1(LD); float accD = LD * ED[0];                             \
        _Pragma("unroll")                                                    \
        for (int r_ = 1; r_ < 8; ++r_) {                                     \
            RA = rotl1(RA); accA = fmaf(RA, EA[r_], accA);                   \
            RC = rotl1(RC); accC = fmaf(RC, EC[r_], accC);                   \
        }                                                                    \
        _Pragma("unroll")                                                    \
        for (int s_ = 2; s_ <= 8; ++s_) {                                    \
            LB = rotr1(LB); accB = fmaf(LB, EB[s_ - 1], accB);               \
            LD = rotr1(LD); accD = fmaf(LD, ED[s_ - 1], accD);               \
        }                                                                    \
        float q = (accA + accB) + (accC + accD);                             \
        p = q * F;                                                           \
        /* renorm bookkeeping for next step (off next chain) */              \
        int bits_ = __builtin_amdgcn_readfirstlane(__float_as_int(p));       \
        int e_ = min(max((bits_ >> 23) & 0xFF, 1), 254);                     \
        kreg = e_ - 127;                                                     \
    }

    for (int ci = 0; ci < nchunk; ++ci) {
        #pragma unroll
        for (int u = 0; u < 8; ++u) {
            float feat = pf[u];
            int   tp   = min(t + 8, NS - 1);
            pf[u] = fb[(size_t)tp * NTAG + j32];       // prefetch t+8
            CRF_STEP(feat)
            ++t;
        }
    }
    // remainder (<8 steps); pf[u] holds feats for t = 1+8*nchunk+u
    #pragma unroll
    for (int u = 0; u < 7; ++u) {
        if (u < rem) {
            CRF_STEP(pf[u])
            ++t;
        }
    }
    #undef CRF_STEP

    // forward score = c*ln2 + log(sum_j p[j]); p duplicated mod 32, so the
    // xor butterfly over masks 1..16 sums the 32 distinct entries.
    float s = p;
    #pragma unroll
    for (int m = 1; m <= 16; m <<= 1)
        s += __shfl_xor(s, m, 64);
    float fwd = (float)creg * LN2 + logf(s);

    // ---- gold score: parallel gather tail (latency-tolerant) ----
    float gold = 0.0f;
    #pragma unroll
    for (int k = 0; k < 8; ++k) {
        int tt = (k << 6) + j;
        if (tt < len) {
            int lab_t = labr[k];
            gold += fb[(size_t)tt * NTAG + lab_t];               // emit
            if (tt > 0)
                gold += trans[(lb[tt - 1] << 5) + lab_t];        // pair
            else
                gold += trans[(TSTART << 5) + lab_t];            // start
            if (tt == len - 1)
                gold += trans[(lab_t << 5) + TSTOP];             // stop
        }
    }
    // reduce gold over all 64 lanes (each (b,t) counted once)
    #pragma unroll
    for (int m = 1; m <= 32; m <<= 1)
        gold += __shfl_xor(gold, m, 64);

    if (j == 0)
        atomicAdd(out, (fwd - gold) * (1.0f / 1024.0f));
}

extern "C" void kernel_launch(void* const* d_in, const int* in_sizes, int n_in,
                              void* d_out, int out_size, void* d_ws, size_t ws_size,
                              hipStream_t stream) {
    const float* feats   = (const float*)d_in[0];
    const int*   labels  = (const int*)d_in[1];
    const int*   lengths = (const int*)d_in[2];
    const float* trans   = (const float*)d_in[3];
    float*       out     = (float*)d_out;

    hipMemsetAsync(out, 0, sizeof(float) * (size_t)out_size, stream);
    crf_fwd<<<dim3(NB), dim3(64), 0, stream>>>(feats, labels, lengths, trans, out);
}